// Round 1
// baseline (298.288 us; speedup 1.0000x reference)
//
#include <hip/hip_runtime.h>
#include <hip/hip_bf16.h>

#define E 1024
#define DK 64
#define SEQ 4096
#define NB 4

typedef short bf16x8 __attribute__((ext_vector_type(8)));
typedef float f32x4 __attribute__((ext_vector_type(4)));

__device__ inline unsigned short f2bf(float f) {
    unsigned int u = __float_as_uint(f);
    u += 0x7fff + ((u >> 16) & 1);   // round-to-nearest-even
    return (unsigned short)(u >> 16);
}

// ---------------- Kernel 0: W [1024][64] fp32 -> Wt [64][1024] bf16 ----------------
__global__ __launch_bounds__(256) void wt_kernel(
    const float* __restrict__ Wq, const float* __restrict__ Wk, const float* __restrict__ Wv,
    unsigned short* __restrict__ wtq, unsigned short* __restrict__ wtk, unsigned short* __restrict__ wtv)
{
    const float* src; unsigned short* dst;
    if (blockIdx.y == 0)      { src = Wq; dst = wtq; }
    else if (blockIdx.y == 1) { src = Wk; dst = wtk; }
    else                      { src = Wv; dst = wtv; }
    int idx = blockIdx.x * 256 + threadIdx.x;   // 0..65535
    int c = idx >> 10;                           // output row (0..63)
    int e = idx & 1023;                          // output col (0..1023)
    dst[idx] = f2bf(src[e * DK + c]);
}

// ---------------- Kernel 1: QKV projection ----------------
// blockIdx.y == 0: Q = input2 @ Wq + bq   (row-major bf16 [B*S][64])
// blockIdx.y == 1: K = input1 @ Wk + bk   (row-major bf16 [B*S][64])
//                  V = input1 @ Wv + bv   (transposed bf16 [B][64][S])
__global__ __launch_bounds__(256) void proj_kernel(
    const float* __restrict__ in_q, const float* __restrict__ in_kv,
    const unsigned short* __restrict__ wtq, const unsigned short* __restrict__ wtk,
    const unsigned short* __restrict__ wtv,
    const float* __restrict__ bq, const float* __restrict__ bk, const float* __restrict__ bv,
    unsigned short* __restrict__ Qw, unsigned short* __restrict__ Kw, unsigned short* __restrict__ Vtw)
{
    const int tid = threadIdx.x;
    const int w = tid >> 6, lane = tid & 63, quad = lane >> 4, l16 = lane & 15;
    const int row0 = blockIdx.x * 64;
    const bool isQ = (blockIdx.y == 0);
    const float* A = isQ ? in_q : in_kv;

    __shared__ __align__(16) unsigned short As[64][72];
    __shared__ __align__(16) unsigned short W0s[64][72];
    __shared__ __align__(16) unsigned short W1s[64][72];

    f32x4 acc0[4] = {};
    f32x4 acc1[4] = {};

    for (int kb = 0; kb < 16; ++kb) {
        // stage A tile: 64 rows x 64 cols fp32 -> bf16
        for (int i = 0; i < 4; ++i) {
            int flat4 = i * 256 + tid;          // 0..1023
            int r = flat4 >> 4;
            int c = (flat4 & 15) << 2;
            float4 v = *reinterpret_cast<const float4*>(&A[(size_t)(row0 + r) * E + kb * 64 + c]);
            ushort4 o;
            o.x = f2bf(v.x); o.y = f2bf(v.y); o.z = f2bf(v.z); o.w = f2bf(v.w);
            *reinterpret_cast<ushort4*>(&As[r][c]) = o;
        }
        // stage W tile(s): already bf16, layout [64 cols][1024 k]
        for (int i = 0; i < 2; ++i) {
            int flat8 = i * 256 + tid;          // 0..511
            int r = flat8 >> 3;
            int c = (flat8 & 7) << 3;
            if (isQ) {
                *reinterpret_cast<uint4*>(&W0s[r][c]) =
                    *reinterpret_cast<const uint4*>(&wtq[(size_t)r * E + kb * 64 + c]);
            } else {
                *reinterpret_cast<uint4*>(&W0s[r][c]) =
                    *reinterpret_cast<const uint4*>(&wtk[(size_t)r * E + kb * 64 + c]);
                *reinterpret_cast<uint4*>(&W1s[r][c]) =
                    *reinterpret_cast<const uint4*>(&wtv[(size_t)r * E + kb * 64 + c]);
            }
        }
        __syncthreads();

        const int mrow = w * 16 + l16;
        for (int ks = 0; ks < 2; ++ks) {
            bf16x8 a = *reinterpret_cast<const bf16x8*>(&As[mrow][ks * 32 + quad * 8]);
            for (int ct = 0; ct < 4; ++ct) {
                bf16x8 b0 = *reinterpret_cast<const bf16x8*>(&W0s[ct * 16 + l16][ks * 32 + quad * 8]);
                acc0[ct] = __builtin_amdgcn_mfma_f32_16x16x32_bf16(a, b0, acc0[ct], 0, 0, 0);
                if (!isQ) {
                    bf16x8 b1 = *reinterpret_cast<const bf16x8*>(&W1s[ct * 16 + l16][ks * 32 + quad * 8]);
                    acc1[ct] = __builtin_amdgcn_mfma_f32_16x16x32_bf16(a, b1, acc1[ct], 0, 0, 0);
                }
            }
        }
        __syncthreads();
    }

    // epilogue: C/D layout col=lane&15, row=quad*4+reg
    const int orow = row0 + w * 16 + quad * 4;
    for (int ct = 0; ct < 4; ++ct) {
        int col = ct * 16 + l16;
        if (isQ) {
            float bias = bq[col];
            for (int r = 0; r < 4; ++r)
                Qw[(size_t)(orow + r) * DK + col] = f2bf(acc0[ct][r] + bias);
        } else {
            float biask = bk[col], biasv = bv[col];
            for (int r = 0; r < 4; ++r) {
                int row = orow + r;
                Kw[(size_t)row * DK + col] = f2bf(acc0[ct][r] + biask);
                int bb = row >> 12;
                int tok = row & 4095;
                Vtw[((size_t)(bb * 64 + col)) * SEQ + tok] = f2bf(acc1[ct][r] + biasv);
            }
        }
    }
}

// ---------------- Kernel 2: flash attention ----------------
// block: 256 threads = 4 waves; 64 queries/block (16/wave); key tiles of 64
__global__ __launch_bounds__(256) void attn_kernel(
    const unsigned short* __restrict__ Qw, const unsigned short* __restrict__ Kw,
    const unsigned short* __restrict__ Vtw, float* __restrict__ out)
{
    const int tid = threadIdx.x;
    const int w = tid >> 6, lane = tid & 63, quad = lane >> 4, l16 = lane & 15;
    const int b = blockIdx.x >> 6;
    const int qt = blockIdx.x & 63;

    __shared__ __align__(16) unsigned short Qs[64][72];
    __shared__ __align__(16) unsigned short Ks[64][72];
    __shared__ __align__(16) unsigned short Vts[64][72];   // [d][key]
    __shared__ __align__(16) unsigned short Ps[4][16][72]; // per-wave P

    // load Q tile (bf16 row-major)
    for (int i = 0; i < 2; ++i) {
        int flat8 = i * 256 + tid;
        int r = flat8 >> 3, c = (flat8 & 7) << 3;
        *reinterpret_cast<uint4*>(&Qs[r][c]) =
            *reinterpret_cast<const uint4*>(&Qw[((size_t)(b * SEQ + qt * 64 + r)) * DK + c]);
    }

    float m[4], l[4];
    f32x4 o[4] = {};
    for (int r = 0; r < 4; ++r) { m[r] = -1e30f; l[r] = 0.f; }

    for (int kt = 0; kt < 64; ++kt) {
        __syncthreads();  // previous iteration done with Ks/Vts (and Q load visible on kt==0)
        for (int i = 0; i < 2; ++i) {
            int flat8 = i * 256 + tid;
            int r = flat8 >> 3, c = (flat8 & 7) << 3;
            *reinterpret_cast<uint4*>(&Ks[r][c]) =
                *reinterpret_cast<const uint4*>(&Kw[((size_t)(b * SEQ + kt * 64 + r)) * DK + c]);
            *reinterpret_cast<uint4*>(&Vts[r][c]) =
                *reinterpret_cast<const uint4*>(&Vtw[((size_t)(b * 64 + r)) * SEQ + kt * 64 + c]);
        }
        __syncthreads();

        // S = (Q K^T) * scale : 4 col-tiles of 16 keys, K-dim 64 = 2 mfma steps
        f32x4 s[4] = {};
        for (int ks = 0; ks < 2; ++ks) {
            bf16x8 a = *reinterpret_cast<const bf16x8*>(&Qs[w * 16 + l16][ks * 32 + quad * 8]);
            for (int ct = 0; ct < 4; ++ct) {
                bf16x8 kb = *reinterpret_cast<const bf16x8*>(&Ks[ct * 16 + l16][ks * 32 + quad * 8]);
                s[ct] = __builtin_amdgcn_mfma_f32_16x16x32_bf16(a, kb, s[ct], 0, 0, 0);
            }
        }
        for (int ct = 0; ct < 4; ++ct)
            for (int r = 0; r < 4; ++r)
                s[ct][r] *= 0.125f;

        // online softmax; row = quad*4 + r lives in the quad's 16 lanes (cols)
        float p[4][4];
        float alpha[4];
        for (int r = 0; r < 4; ++r) {
            float mx = fmaxf(fmaxf(s[0][r], s[1][r]), fmaxf(s[2][r], s[3][r]));
            for (int off = 1; off < 16; off <<= 1)
                mx = fmaxf(mx, __shfl_xor(mx, off, 64));
            float mnew = fmaxf(m[r], mx);
            alpha[r] = __expf(m[r] - mnew);
            float rs = 0.f;
            for (int ct = 0; ct < 4; ++ct) {
                float pv = __expf(s[ct][r] - mnew);
                p[ct][r] = pv;
                rs += pv;
            }
            for (int off = 1; off < 16; off <<= 1)
                rs += __shfl_xor(rs, off, 64);
            l[r] = l[r] * alpha[r] + rs;
            m[r] = mnew;
        }

        // rescale O, store P (C-layout -> LDS row-major [q][key])
        for (int ct = 0; ct < 4; ++ct)
            for (int r = 0; r < 4; ++r) {
                o[ct][r] *= alpha[r];
                Ps[w][quad * 4 + r][ct * 16 + l16] = f2bf(p[ct][r]);
            }
        __syncthreads();  // make own P writes visible (conservative, round 0)

        // O += P @ V : A = P [16q x 64key], B = V [64key x 64d] via Vts[d][key]
        for (int ks = 0; ks < 2; ++ks) {
            bf16x8 a = *reinterpret_cast<const bf16x8*>(&Ps[w][l16][ks * 32 + quad * 8]);
            for (int ct = 0; ct < 4; ++ct) {
                bf16x8 vb = *reinterpret_cast<const bf16x8*>(&Vts[ct * 16 + l16][ks * 32 + quad * 8]);
                o[ct] = __builtin_amdgcn_mfma_f32_16x16x32_bf16(a, vb, o[ct], 0, 0, 0);
            }
        }
    }

    const int qrow = b * SEQ + qt * 64 + w * 16 + quad * 4;
    for (int ct = 0; ct < 4; ++ct)
        for (int r = 0; r < 4; ++r)
            out[((size_t)(qrow + r)) * DK + ct * 16 + l16] = o[ct][r] / l[r];
}

extern "C" void kernel_launch(void* const* d_in, const int* in_sizes, int n_in,
                              void* d_out, int out_size, void* d_ws, size_t ws_size,
                              hipStream_t stream) {
    const float* input1 = (const float*)d_in[0];
    const float* input2 = (const float*)d_in[1];
    const float* Wq = (const float*)d_in[2];
    const float* bq = (const float*)d_in[3];
    const float* Wk = (const float*)d_in[4];
    const float* bk = (const float*)d_in[5];
    const float* Wv = (const float*)d_in[6];
    const float* bv = (const float*)d_in[7];
    float* out = (float*)d_out;

    char* ws = (char*)d_ws;
    unsigned short* wtq = (unsigned short*)(ws + 0);
    unsigned short* wtk = (unsigned short*)(ws + 131072);
    unsigned short* wtv = (unsigned short*)(ws + 262144);
    unsigned short* Qw  = (unsigned short*)(ws + 393216);
    unsigned short* Kw  = (unsigned short*)(ws + 2490368);
    unsigned short* Vtw = (unsigned short*)(ws + 4587520);

    wt_kernel<<<dim3(256, 3), 256, 0, stream>>>(Wq, Wk, Wv, wtq, wtk, wtv);
    proj_kernel<<<dim3(256, 2), 256, 0, stream>>>(input2, input1, wtq, wtk, wtv,
                                                  bq, bk, bv, Qw, Kw, Vtw);
    attn_kernel<<<dim3(256), 256, 0, stream>>>(Qw, Kw, Vtw, out);
}